// Round 1
// baseline (507.547 us; speedup 1.0000x reference)
//
#include <hip/hip_runtime.h>
#include <math.h>

// ---------------- helpers ----------------
__device__ __forceinline__ float4 ld4(const float* p) { return *reinterpret_cast<const float4*>(p); }
__device__ __forceinline__ void st4(float* p, float4 v) { *reinterpret_cast<float4*>(p) = v; }

// ---------------- CSR build ----------------
__global__ __launch_bounds__(256) void k_count(const int* __restrict__ dst, int* __restrict__ deg, int E) {
    int e = blockIdx.x * 256 + threadIdx.x;
    if (e < E) atomicAdd(&deg[dst[e]], 1);
}

__global__ __launch_bounds__(256) void k_dinv(const int* __restrict__ deg, float* __restrict__ dinv, int n) {
    int i = blockIdx.x * 256 + threadIdx.x;
    if (i < n) dinv[i] = 1.0f / sqrtf((float)deg[i] + 1.0f);
}

__global__ __launch_bounds__(256) void k_reduce256(const int* __restrict__ deg, int* __restrict__ bsum, int n) {
    __shared__ int s[256];
    int t = threadIdx.x;
    int i = blockIdx.x * 256 + t;
    s[t] = (i < n) ? deg[i] : 0;
    __syncthreads();
    for (int off = 128; off > 0; off >>= 1) {
        if (t < off) s[t] += s[t + off];
        __syncthreads();
    }
    if (t == 0) bsum[blockIdx.x] = s[0];
}

__global__ __launch_bounds__(256) void k_scan_small(const int* __restrict__ bsum, int* __restrict__ boff, int nb) {
    __shared__ int s[256];
    int t = threadIdx.x;
    int v = (t < nb) ? bsum[t] : 0;
    s[t] = v;
    __syncthreads();
    for (int off = 1; off < 256; off <<= 1) {
        int x = (t >= off) ? s[t - off] : 0;
        __syncthreads();
        s[t] += x;
        __syncthreads();
    }
    if (t < nb) boff[t] = s[t] - v;  // exclusive
}

__global__ __launch_bounds__(256) void k_scan_final(const int* __restrict__ deg, const int* __restrict__ boff,
                                                    int* __restrict__ row_off, int* __restrict__ cursor, int n) {
    __shared__ int s[256];
    int t = threadIdx.x;
    int i = blockIdx.x * 256 + t;
    int v = (i < n) ? deg[i] : 0;
    s[t] = v;
    __syncthreads();
    for (int off = 1; off < 256; off <<= 1) {
        int x = (t >= off) ? s[t - off] : 0;
        __syncthreads();
        s[t] += x;
        __syncthreads();
    }
    int incl = s[t] + boff[blockIdx.x];
    if (i < n) {
        int ex = incl - v;
        row_off[i] = ex;
        cursor[i]  = ex;
        if (i == n - 1) row_off[n] = incl;
    }
}

__global__ __launch_bounds__(256) void k_fill(const int* __restrict__ src, const int* __restrict__ dst,
                                              const float* __restrict__ dinv, int* __restrict__ cursor,
                                              int* __restrict__ csrc, float* __restrict__ cnorm, int E) {
    int e = blockIdx.x * 256 + threadIdx.x;
    if (e < E) {
        int s = src[e], d = dst[e];
        int pos = atomicAdd(&cursor[d], 1);
        csrc[pos]  = s;
        cnorm[pos] = dinv[s] * dinv[d];
    }
}

// ---------------- fp32 tiled GEMM:  O[nrows x NC] = X[nrows x 128] @ W[128 x NC] ----------------
// 128 threads, thread tile 8x8, K staged in two halves of 64 -> 48 KB LDS.
#define FMA4(r, xv, j)                                         \
    do {                                                       \
        acc[r][0] += (xv) * wlo[j].x; acc[r][1] += (xv) * wlo[j].y; \
        acc[r][2] += (xv) * wlo[j].z; acc[r][3] += (xv) * wlo[j].w; \
        acc[r][4] += (xv) * whi[j].x; acc[r][5] += (xv) * whi[j].y; \
        acc[r][6] += (xv) * whi[j].z; acc[r][7] += (xv) * whi[j].w; \
    } while (0)

template <int NC>
__global__ __launch_bounds__(128) void k_gemm(const float* __restrict__ X, const float* __restrict__ W,
                                              float* __restrict__ O, int nrows) {
    constexpr int ROWS  = 8192 / NC;  // 64 (NC=128) or 128 (NC=64)
    constexpr int TCOLS = NC / 8;     // 16 or 8
    __shared__ float sW[64 * NC];     // K-half x NC
    __shared__ float sX[ROWS * 64];   // ROWS x K-half

    const int tid  = threadIdx.x;
    const int tc   = tid % TCOLS;
    const int tr   = tid / TCOLS;
    const int row0 = blockIdx.x * ROWS;

    float acc[8][8];
#pragma unroll
    for (int r = 0; r < 8; ++r)
#pragma unroll
        for (int c = 0; c < 8; ++c) acc[r][c] = 0.0f;

    for (int kh = 0; kh < 2; ++kh) {
        // stage W[kh*64 .. +64][0..NC)
        for (int i = tid; i < 16 * NC; i += 128) {  // 16*NC float4s
            int kk = i / (NC / 4), c4 = i % (NC / 4);
            reinterpret_cast<float4*>(sW)[i] = ld4(W + (size_t)(kh * 64 + kk) * NC + c4 * 4);
        }
        // stage X[row0 .. row0+ROWS)[kh*64 .. +64)
        for (int i = tid; i < ROWS * 16; i += 128) {
            int r = i / 16, c4 = i % 16;
            int grow = row0 + r;
            float4 v = make_float4(0.f, 0.f, 0.f, 0.f);
            if (grow < nrows) v = ld4(X + (size_t)grow * 128 + kh * 64 + c4 * 4);
            reinterpret_cast<float4*>(sX)[i] = v;
        }
        __syncthreads();

#pragma unroll
        for (int k4 = 0; k4 < 16; ++k4) {
            float4 xa[8];
#pragma unroll
            for (int r = 0; r < 8; ++r)
                xa[r] = *reinterpret_cast<const float4*>(&sX[(tr * 8 + r) * 64 + k4 * 4]);
            float4 wlo[4], whi[4];
#pragma unroll
            for (int j = 0; j < 4; ++j) {
                wlo[j] = *reinterpret_cast<const float4*>(&sW[(k4 * 4 + j) * NC + tc * 8]);
                whi[j] = *reinterpret_cast<const float4*>(&sW[(k4 * 4 + j) * NC + tc * 8 + 4]);
            }
#pragma unroll
            for (int r = 0; r < 8; ++r) {
                float4 xr = xa[r];
                FMA4(r, xr.x, 0);
                FMA4(r, xr.y, 1);
                FMA4(r, xr.z, 2);
                FMA4(r, xr.w, 3);
            }
        }
        __syncthreads();
    }

#pragma unroll
    for (int r = 0; r < 8; ++r) {
        int grow = row0 + tr * 8 + r;
        if (grow < nrows) {
            float4 o0 = make_float4(acc[r][0], acc[r][1], acc[r][2], acc[r][3]);
            float4 o1 = make_float4(acc[r][4], acc[r][5], acc[r][6], acc[r][7]);
            st4(O + (size_t)grow * NC + tc * 8, o0);
            st4(O + (size_t)grow * NC + tc * 8 + 4, o1);
        }
    }
}

// ---------------- aggregation (128 feats) + bias + relu ----------------
// 32 lanes per node, float4 per lane.
__global__ __launch_bounds__(256) void k_agg_relu(const float* __restrict__ H, const int* __restrict__ roff,
                                                  const int* __restrict__ csrc, const float* __restrict__ cnorm,
                                                  const float* __restrict__ dinv, const float* __restrict__ bias,
                                                  float* __restrict__ O, int n) {
    int t    = blockIdx.x * 256 + threadIdx.x;
    int node = t >> 5;
    int f    = (t & 31) * 4;
    if (node >= n) return;

    float di = dinv[node];
    float sc = di * di;
    float4 h0 = ld4(H + (size_t)node * 128 + f);
    float4 acc;
    acc.x = h0.x * sc; acc.y = h0.y * sc; acc.z = h0.z * sc; acc.w = h0.w * sc;

    int e  = roff[node];
    int e1 = roff[node + 1];
    for (; e + 1 < e1; e += 2) {
        int s0 = csrc[e], s1 = csrc[e + 1];
        float n0 = cnorm[e], n1 = cnorm[e + 1];
        float4 a = ld4(H + (size_t)s0 * 128 + f);
        float4 b = ld4(H + (size_t)s1 * 128 + f);
        acc.x += a.x * n0 + b.x * n1;
        acc.y += a.y * n0 + b.y * n1;
        acc.z += a.z * n0 + b.z * n1;
        acc.w += a.w * n0 + b.w * n1;
    }
    if (e < e1) {
        int s0 = csrc[e];
        float n0 = cnorm[e];
        float4 a = ld4(H + (size_t)s0 * 128 + f);
        acc.x += a.x * n0; acc.y += a.y * n0; acc.z += a.z * n0; acc.w += a.w * n0;
    }

    float4 bv = ld4(bias + f);
    acc.x = fmaxf(acc.x + bv.x, 0.0f);
    acc.y = fmaxf(acc.y + bv.y, 0.0f);
    acc.z = fmaxf(acc.z + bv.z, 0.0f);
    acc.w = fmaxf(acc.w + bv.w, 0.0f);
    st4(O + (size_t)node * 128 + f, acc);
}

// ---------------- aggregation (64 feats) + bias + log_softmax ----------------
// one 64-lane wave per node.
__global__ __launch_bounds__(256) void k_agg_softmax(const float* __restrict__ H, const int* __restrict__ roff,
                                                     const int* __restrict__ csrc, const float* __restrict__ cnorm,
                                                     const float* __restrict__ dinv, const float* __restrict__ bias,
                                                     float* __restrict__ O, int n) {
    int t    = blockIdx.x * 256 + threadIdx.x;
    int node = t >> 6;
    int f    = t & 63;
    if (node >= n) return;

    float di  = dinv[node];
    float acc = H[(size_t)node * 64 + f] * di * di;

    int e  = roff[node];
    int e1 = roff[node + 1];
    for (; e + 1 < e1; e += 2) {
        int s0 = csrc[e], s1 = csrc[e + 1];
        float n0 = cnorm[e], n1 = cnorm[e + 1];
        acc += H[(size_t)s0 * 64 + f] * n0 + H[(size_t)s1 * 64 + f] * n1;
    }
    if (e < e1) acc += H[(size_t)csrc[e] * 64 + f] * cnorm[e];

    float v = acc + bias[f];

    float m = v;
#pragma unroll
    for (int off = 32; off > 0; off >>= 1) m = fmaxf(m, __shfl_xor(m, off));
    float ex = expf(v - m);
    float ssum = ex;
#pragma unroll
    for (int off = 32; off > 0; off >>= 1) ssum += __shfl_xor(ssum, off);

    O[(size_t)node * 64 + f] = (v - m) - logf(ssum);
}

// ---------------- launch ----------------
extern "C" void kernel_launch(void* const* d_in, const int* in_sizes, int n_in,
                              void* d_out, int out_size, void* d_ws, size_t ws_size,
                              hipStream_t stream) {
    const float* x  = (const float*)d_in[0];
    const int*   ei = (const int*)d_in[1];
    const float* W1 = (const float*)d_in[2];
    const float* b1 = (const float*)d_in[3];
    const float* W2 = (const float*)d_in[4];
    const float* b2 = (const float*)d_in[5];
    const float* W3 = (const float*)d_in[6];
    const float* b3 = (const float*)d_in[7];
    float* out = (float*)d_out;

    const int N = in_sizes[0] / 128;
    const int E = in_sizes[1] / 2;
    const int* src = ei;
    const int* dst = ei + E;

    char* ws = (char*)d_ws;
    size_t off = 0;
    auto alloc = [&](size_t bytes) -> char* {
        char* p = ws + off;
        off = (off + bytes + 255) & ~(size_t)255;
        return p;
    };
    int nb = (N + 255) / 256;
    int*   deg     = (int*)alloc((size_t)N * 4);
    int*   cursor  = (int*)alloc((size_t)N * 4);
    int*   row_off = (int*)alloc(((size_t)N + 1) * 4);
    float* dinv    = (float*)alloc((size_t)N * 4);
    int*   bsum    = (int*)alloc((size_t)nb * 4);
    int*   boff    = (int*)alloc((size_t)nb * 4);
    int*   csrc    = (int*)alloc((size_t)E * 4);
    float* cnorm   = (float*)alloc((size_t)E * 4);
    float* bufA    = (float*)alloc((size_t)N * 128 * 4);
    float* bufB    = (float*)alloc((size_t)N * 128 * 4);
    (void)ws_size; (void)n_in; (void)out_size;

    hipMemsetAsync(deg, 0, (size_t)N * 4, stream);
    k_count<<<(E + 255) / 256, 256, 0, stream>>>(dst, deg, E);
    k_dinv<<<(N + 255) / 256, 256, 0, stream>>>(deg, dinv, N);
    k_reduce256<<<nb, 256, 0, stream>>>(deg, bsum, N);
    k_scan_small<<<1, 256, 0, stream>>>(bsum, boff, nb);
    k_scan_final<<<nb, 256, 0, stream>>>(deg, boff, row_off, cursor, N);
    k_fill<<<(E + 255) / 256, 256, 0, stream>>>(src, dst, dinv, cursor, csrc, cnorm, E);

    // layer 1
    k_gemm<128><<<(N + 63) / 64, 128, 0, stream>>>(x, W1, bufA, N);
    k_agg_relu<<<((size_t)N * 32 + 255) / 256, 256, 0, stream>>>(bufA, row_off, csrc, cnorm, dinv, b1, bufB, N);
    // layer 2
    k_gemm<128><<<(N + 63) / 64, 128, 0, stream>>>(bufB, W2, bufA, N);
    k_agg_relu<<<((size_t)N * 32 + 255) / 256, 256, 0, stream>>>(bufA, row_off, csrc, cnorm, dinv, b2, bufB, N);
    // layer 3 + log_softmax
    k_gemm<64><<<(N + 127) / 128, 128, 0, stream>>>(bufB, W3, bufA, N);
    k_agg_softmax<<<(N + 3) / 4, 256, 0, stream>>>(bufA, row_off, csrc, cnorm, dinv, b3, out, N);
}

// Round 2
// 423.534 us; speedup vs baseline: 1.1984x; 1.1984x over previous
//
#include <hip/hip_runtime.h>
#include <math.h>

// ---------------- helpers ----------------
__device__ __forceinline__ float4 ld4(const float* p) { return *reinterpret_cast<const float4*>(p); }
__device__ __forceinline__ void st4(float* p, float4 v) { *reinterpret_cast<float4*>(p) = v; }

// ---------------- CSR build ----------------
__global__ __launch_bounds__(256) void k_count(const int* __restrict__ dst, int* __restrict__ deg, int E) {
    int e = blockIdx.x * 256 + threadIdx.x;
    if (e < E) atomicAdd(&deg[dst[e]], 1);
}

__global__ __launch_bounds__(256) void k_dinv(const int* __restrict__ deg, float* __restrict__ dinv, int n) {
    int i = blockIdx.x * 256 + threadIdx.x;
    if (i < n) dinv[i] = 1.0f / sqrtf((float)deg[i] + 1.0f);
}

__global__ __launch_bounds__(256) void k_reduce256(const int* __restrict__ deg, int* __restrict__ bsum, int n) {
    __shared__ int s[256];
    int t = threadIdx.x;
    int i = blockIdx.x * 256 + t;
    s[t] = (i < n) ? deg[i] : 0;
    __syncthreads();
    for (int off = 128; off > 0; off >>= 1) {
        if (t < off) s[t] += s[t + off];
        __syncthreads();
    }
    if (t == 0) bsum[blockIdx.x] = s[0];
}

__global__ __launch_bounds__(256) void k_scan_small(const int* __restrict__ bsum, int* __restrict__ boff, int nb) {
    __shared__ int s[256];
    int t = threadIdx.x;
    int v = (t < nb) ? bsum[t] : 0;
    s[t] = v;
    __syncthreads();
    for (int off = 1; off < 256; off <<= 1) {
        int x = (t >= off) ? s[t - off] : 0;
        __syncthreads();
        s[t] += x;
        __syncthreads();
    }
    if (t < nb) boff[t] = s[t] - v;  // exclusive
}

__global__ __launch_bounds__(256) void k_scan_final(const int* __restrict__ deg, const int* __restrict__ boff,
                                                    int* __restrict__ row_off, int* __restrict__ cursor, int n) {
    __shared__ int s[256];
    int t = threadIdx.x;
    int i = blockIdx.x * 256 + t;
    int v = (i < n) ? deg[i] : 0;
    s[t] = v;
    __syncthreads();
    for (int off = 1; off < 256; off <<= 1) {
        int x = (t >= off) ? s[t - off] : 0;
        __syncthreads();
        s[t] += x;
        __syncthreads();
    }
    int incl = s[t] + boff[blockIdx.x];
    if (i < n) {
        int ex = incl - v;
        row_off[i] = ex;
        cursor[i]  = ex;
        if (i == n - 1) row_off[n] = incl;
    }
}

__global__ __launch_bounds__(256) void k_fill(const int* __restrict__ src, const int* __restrict__ dst,
                                              const float* __restrict__ dinv, int* __restrict__ cursor,
                                              int* __restrict__ csrc, float* __restrict__ cnorm, int E) {
    int e = blockIdx.x * 256 + threadIdx.x;
    if (e < E) {
        int s = src[e], d = dst[e];
        int pos = atomicAdd(&cursor[d], 1);
        csrc[pos]  = s;
        cnorm[pos] = dinv[s] * dinv[d];
    }
}

// ---------------- fp32 tiled GEMM, NC=128:  O[nrows x 128] = X[nrows x 128] @ W[128 x 128] ----
// 256 threads, tile 64x128, thread tile 4 rows x 8 cols (cols tc*4 and 64+tc*4).
// KC=64 staged twice. sX padded to 68 floats/row -> fragment reads are 2-way (free).
__global__ __launch_bounds__(256) void k_gemm128(const float* __restrict__ X, const float* __restrict__ W,
                                                 float* __restrict__ O, int nrows) {
    __shared__ float sW[64 * 128];
    __shared__ float sX[64 * 68];

    const int tid  = threadIdx.x;
    const int tc   = tid & 15;   // 0..15 -> cols tc*4, 64+tc*4
    const int tr   = tid >> 4;   // 0..15 -> rows tr*4 .. tr*4+3
    const int row0 = blockIdx.x * 64;

    float acc[4][8];
#pragma unroll
    for (int r = 0; r < 4; ++r)
#pragma unroll
        for (int c = 0; c < 8; ++c) acc[r][c] = 0.0f;

    for (int kc = 0; kc < 2; ++kc) {
        // stage W[kc*64 .. +64)[0..128): 2048 float4s
#pragma unroll
        for (int i = 0; i < 8; ++i) {
            int idx = tid + i * 256;
            int kk = idx >> 5, c4 = idx & 31;
            reinterpret_cast<float4*>(sW)[idx] = ld4(W + (size_t)(kc * 64 + kk) * 128 + c4 * 4);
        }
        // stage X[row0..row0+64)[kc*64 .. +64): 1024 float4s, padded rows
#pragma unroll
        for (int i = 0; i < 4; ++i) {
            int idx = tid + i * 256;
            int r = idx >> 4, c4 = idx & 15;
            int grow = row0 + r;
            float4 v = make_float4(0.f, 0.f, 0.f, 0.f);
            if (grow < nrows) v = ld4(X + (size_t)grow * 128 + kc * 64 + c4 * 4);
            *reinterpret_cast<float4*>(&sX[r * 68 + c4 * 4]) = v;
        }
        __syncthreads();

#pragma unroll
        for (int k4 = 0; k4 < 16; ++k4) {
            float4 xa[4];
#pragma unroll
            for (int r = 0; r < 4; ++r)
                xa[r] = *reinterpret_cast<const float4*>(&sX[(tr * 4 + r) * 68 + k4 * 4]);
            float4 wlo[4], whi[4];
#pragma unroll
            for (int j = 0; j < 4; ++j) {
                wlo[j] = *reinterpret_cast<const float4*>(&sW[(k4 * 4 + j) * 128 + tc * 4]);
                whi[j] = *reinterpret_cast<const float4*>(&sW[(k4 * 4 + j) * 128 + 64 + tc * 4]);
            }
#pragma unroll
            for (int r = 0; r < 4; ++r) {
                float xs[4] = {xa[r].x, xa[r].y, xa[r].z, xa[r].w};
#pragma unroll
                for (int j = 0; j < 4; ++j) {
                    acc[r][0] += xs[j] * wlo[j].x;
                    acc[r][1] += xs[j] * wlo[j].y;
                    acc[r][2] += xs[j] * wlo[j].z;
                    acc[r][3] += xs[j] * wlo[j].w;
                    acc[r][4] += xs[j] * whi[j].x;
                    acc[r][5] += xs[j] * whi[j].y;
                    acc[r][6] += xs[j] * whi[j].z;
                    acc[r][7] += xs[j] * whi[j].w;
                }
            }
        }
        __syncthreads();
    }

#pragma unroll
    for (int r = 0; r < 4; ++r) {
        int grow = row0 + tr * 4 + r;
        if (grow < nrows) {
            st4(O + (size_t)grow * 128 + tc * 4, make_float4(acc[r][0], acc[r][1], acc[r][2], acc[r][3]));
            st4(O + (size_t)grow * 128 + 64 + tc * 4, make_float4(acc[r][4], acc[r][5], acc[r][6], acc[r][7]));
        }
    }
}

// ---------------- fp32 tiled GEMM, NC=64 ----------------
// 256 threads, tile 64x64, thread tile 4 rows x 4 cols.
__global__ __launch_bounds__(256) void k_gemm64(const float* __restrict__ X, const float* __restrict__ W,
                                                float* __restrict__ O, int nrows) {
    __shared__ float sW[64 * 64];
    __shared__ float sX[64 * 68];

    const int tid  = threadIdx.x;
    const int tc   = tid & 15;   // cols tc*4
    const int tr   = tid >> 4;   // rows tr*4
    const int row0 = blockIdx.x * 64;

    float acc[4][4];
#pragma unroll
    for (int r = 0; r < 4; ++r)
#pragma unroll
        for (int c = 0; c < 4; ++c) acc[r][c] = 0.0f;

    for (int kc = 0; kc < 2; ++kc) {
        // stage W[kc*64 .. +64)[0..64): 1024 float4s
#pragma unroll
        for (int i = 0; i < 4; ++i) {
            int idx = tid + i * 256;
            int kk = idx >> 4, c4 = idx & 15;
            reinterpret_cast<float4*>(sW)[idx] = ld4(W + (size_t)(kc * 64 + kk) * 64 + c4 * 4);
        }
#pragma unroll
        for (int i = 0; i < 4; ++i) {
            int idx = tid + i * 256;
            int r = idx >> 4, c4 = idx & 15;
            int grow = row0 + r;
            float4 v = make_float4(0.f, 0.f, 0.f, 0.f);
            if (grow < nrows) v = ld4(X + (size_t)grow * 128 + kc * 64 + c4 * 4);
            *reinterpret_cast<float4*>(&sX[r * 68 + c4 * 4]) = v;
        }
        __syncthreads();

#pragma unroll
        for (int k4 = 0; k4 < 16; ++k4) {
            float4 xa[4];
#pragma unroll
            for (int r = 0; r < 4; ++r)
                xa[r] = *reinterpret_cast<const float4*>(&sX[(tr * 4 + r) * 68 + k4 * 4]);
            float4 w[4];
#pragma unroll
            for (int j = 0; j < 4; ++j)
                w[j] = *reinterpret_cast<const float4*>(&sW[(k4 * 4 + j) * 64 + tc * 4]);
#pragma unroll
            for (int r = 0; r < 4; ++r) {
                float xs[4] = {xa[r].x, xa[r].y, xa[r].z, xa[r].w};
#pragma unroll
                for (int j = 0; j < 4; ++j) {
                    acc[r][0] += xs[j] * w[j].x;
                    acc[r][1] += xs[j] * w[j].y;
                    acc[r][2] += xs[j] * w[j].z;
                    acc[r][3] += xs[j] * w[j].w;
                }
            }
        }
        __syncthreads();
    }

#pragma unroll
    for (int r = 0; r < 4; ++r) {
        int grow = row0 + tr * 4 + r;
        if (grow < nrows)
            st4(O + (size_t)grow * 64 + tc * 4, make_float4(acc[r][0], acc[r][1], acc[r][2], acc[r][3]));
    }
}

// ---------------- aggregation (128 feats) + bias + relu ----------------
__global__ __launch_bounds__(256) void k_agg_relu(const float* __restrict__ H, const int* __restrict__ roff,
                                                  const int* __restrict__ csrc, const float* __restrict__ cnorm,
                                                  const float* __restrict__ dinv, const float* __restrict__ bias,
                                                  float* __restrict__ O, int n) {
    int t    = blockIdx.x * 256 + threadIdx.x;
    int node = t >> 5;
    int f    = (t & 31) * 4;
    if (node >= n) return;

    float di = dinv[node];
    float sc = di * di;
    float4 h0 = ld4(H + (size_t)node * 128 + f);
    float4 acc;
    acc.x = h0.x * sc; acc.y = h0.y * sc; acc.z = h0.z * sc; acc.w = h0.w * sc;

    int e  = roff[node];
    int e1 = roff[node + 1];
    for (; e + 1 < e1; e += 2) {
        int s0 = csrc[e], s1 = csrc[e + 1];
        float n0 = cnorm[e], n1 = cnorm[e + 1];
        float4 a = ld4(H + (size_t)s0 * 128 + f);
        float4 b = ld4(H + (size_t)s1 * 128 + f);
        acc.x += a.x * n0 + b.x * n1;
        acc.y += a.y * n0 + b.y * n1;
        acc.z += a.z * n0 + b.z * n1;
        acc.w += a.w * n0 + b.w * n1;
    }
    if (e < e1) {
        int s0 = csrc[e];
        float n0 = cnorm[e];
        float4 a = ld4(H + (size_t)s0 * 128 + f);
        acc.x += a.x * n0; acc.y += a.y * n0; acc.z += a.z * n0; acc.w += a.w * n0;
    }

    float4 bv = ld4(bias + f);
    acc.x = fmaxf(acc.x + bv.x, 0.0f);
    acc.y = fmaxf(acc.y + bv.y, 0.0f);
    acc.z = fmaxf(acc.z + bv.z, 0.0f);
    acc.w = fmaxf(acc.w + bv.w, 0.0f);
    st4(O + (size_t)node * 128 + f, acc);
}

// ---------------- aggregation (64 feats) + bias + log_softmax ----------------
__global__ __launch_bounds__(256) void k_agg_softmax(const float* __restrict__ H, const int* __restrict__ roff,
                                                     const int* __restrict__ csrc, const float* __restrict__ cnorm,
                                                     const float* __restrict__ dinv, const float* __restrict__ bias,
                                                     float* __restrict__ O, int n) {
    int t    = blockIdx.x * 256 + threadIdx.x;
    int node = t >> 6;
    int f    = t & 63;
    if (node >= n) return;

    float di  = dinv[node];
    float acc = H[(size_t)node * 64 + f] * di * di;

    int e  = roff[node];
    int e1 = roff[node + 1];
    for (; e + 1 < e1; e += 2) {
        int s0 = csrc[e], s1 = csrc[e + 1];
        float n0 = cnorm[e], n1 = cnorm[e + 1];
        acc += H[(size_t)s0 * 64 + f] * n0 + H[(size_t)s1 * 64 + f] * n1;
    }
    if (e < e1) acc += H[(size_t)csrc[e] * 64 + f] * cnorm[e];

    float v = acc + bias[f];

    float m = v;
#pragma unroll
    for (int off = 32; off > 0; off >>= 1) m = fmaxf(m, __shfl_xor(m, off));
    float ex = expf(v - m);
    float ssum = ex;
#pragma unroll
    for (int off = 32; off > 0; off >>= 1) ssum += __shfl_xor(ssum, off);

    O[(size_t)node * 64 + f] = (v - m) - logf(ssum);
}

// ---------------- launch ----------------
extern "C" void kernel_launch(void* const* d_in, const int* in_sizes, int n_in,
                              void* d_out, int out_size, void* d_ws, size_t ws_size,
                              hipStream_t stream) {
    const float* x  = (const float*)d_in[0];
    const int*   ei = (const int*)d_in[1];
    const float* W1 = (const float*)d_in[2];
    const float* b1 = (const float*)d_in[3];
    const float* W2 = (const float*)d_in[4];
    const float* b2 = (const float*)d_in[5];
    const float* W3 = (const float*)d_in[6];
    const float* b3 = (const float*)d_in[7];
    float* out = (float*)d_out;

    const int N = in_sizes[0] / 128;
    const int E = in_sizes[1] / 2;
    const int* src = ei;
    const int* dst = ei + E;

    char* ws = (char*)d_ws;
    size_t off = 0;
    auto alloc = [&](size_t bytes) -> char* {
        char* p = ws + off;
        off = (off + bytes + 255) & ~(size_t)255;
        return p;
    };
    int nb = (N + 255) / 256;
    int*   deg     = (int*)alloc((size_t)N * 4);
    int*   cursor  = (int*)alloc((size_t)N * 4);
    int*   row_off = (int*)alloc(((size_t)N + 1) * 4);
    float* dinv    = (float*)alloc((size_t)N * 4);
    int*   bsum    = (int*)alloc((size_t)nb * 4);
    int*   boff    = (int*)alloc((size_t)nb * 4);
    int*   csrc    = (int*)alloc((size_t)E * 4);
    float* cnorm   = (float*)alloc((size_t)E * 4);
    float* bufA    = (float*)alloc((size_t)N * 128 * 4);
    float* bufB    = (float*)alloc((size_t)N * 128 * 4);
    (void)ws_size; (void)n_in; (void)out_size;

    hipMemsetAsync(deg, 0, (size_t)N * 4, stream);
    k_count<<<(E + 255) / 256, 256, 0, stream>>>(dst, deg, E);
    k_dinv<<<(N + 255) / 256, 256, 0, stream>>>(deg, dinv, N);
    k_reduce256<<<nb, 256, 0, stream>>>(deg, bsum, N);
    k_scan_small<<<1, 256, 0, stream>>>(bsum, boff, nb);
    k_scan_final<<<nb, 256, 0, stream>>>(deg, boff, row_off, cursor, N);
    k_fill<<<(E + 255) / 256, 256, 0, stream>>>(src, dst, dinv, cursor, csrc, cnorm, E);

    int gemm_blocks = (N + 63) / 64;
    // layer 1
    k_gemm128<<<gemm_blocks, 256, 0, stream>>>(x, W1, bufA, N);
    k_agg_relu<<<((size_t)N * 32 + 255) / 256, 256, 0, stream>>>(bufA, row_off, csrc, cnorm, dinv, b1, bufB, N);
    // layer 2
    k_gemm128<<<gemm_blocks, 256, 0, stream>>>(bufB, W2, bufA, N);
    k_agg_relu<<<((size_t)N * 32 + 255) / 256, 256, 0, stream>>>(bufA, row_off, csrc, cnorm, dinv, b2, bufB, N);
    // layer 3 + log_softmax
    k_gemm64<<<gemm_blocks, 256, 0, stream>>>(bufB, W3, bufA, N);
    k_agg_softmax<<<(N + 3) / 4, 256, 0, stream>>>(bufA, row_off, csrc, cnorm, dinv, b3, out, N);
}

// Round 3
// 378.467 us; speedup vs baseline: 1.3411x; 1.1191x over previous
//
#include <hip/hip_runtime.h>
#include <math.h>

// ---------------- helpers ----------------
__device__ __forceinline__ float4 ld4(const float* p) { return *reinterpret_cast<const float4*>(p); }
__device__ __forceinline__ void st4(float* p, float4 v) { *reinterpret_cast<float4*>(p) = v; }

__device__ __forceinline__ float bf2f(unsigned int u) { return __uint_as_float(u << 16); }
__device__ __forceinline__ unsigned int f2bf1(float f) {
    unsigned int x = __float_as_uint(f);
    return (x + 0x7fffu + ((x >> 16) & 1u)) >> 16;  // RNE
}
__device__ __forceinline__ unsigned int f2bf2(float lo, float hi) {
    return f2bf1(lo) | (f2bf1(hi) << 16);
}
__device__ __forceinline__ void unpack8(uint4 v, float* f) {
    f[0] = bf2f(v.x & 0xffffu); f[1] = bf2f(v.x >> 16);
    f[2] = bf2f(v.y & 0xffffu); f[3] = bf2f(v.y >> 16);
    f[4] = bf2f(v.z & 0xffffu); f[5] = bf2f(v.z >> 16);
    f[6] = bf2f(v.w & 0xffffu); f[7] = bf2f(v.w >> 16);
}

// ---------------- CSR build ----------------
__global__ __launch_bounds__(256) void k_count(const int* __restrict__ dst, int* __restrict__ deg, int E) {
    int e = blockIdx.x * 256 + threadIdx.x;
    if (e < E) atomicAdd(&deg[dst[e]], 1);
}

__global__ __launch_bounds__(256) void k_dinv(const int* __restrict__ deg, float* __restrict__ dinv, int n) {
    int i = blockIdx.x * 256 + threadIdx.x;
    if (i < n) dinv[i] = 1.0f / sqrtf((float)deg[i] + 1.0f);
}

__global__ __launch_bounds__(256) void k_reduce256(const int* __restrict__ deg, int* __restrict__ bsum, int n) {
    __shared__ int s[256];
    int t = threadIdx.x;
    int i = blockIdx.x * 256 + t;
    s[t] = (i < n) ? deg[i] : 0;
    __syncthreads();
    for (int off = 128; off > 0; off >>= 1) {
        if (t < off) s[t] += s[t + off];
        __syncthreads();
    }
    if (t == 0) bsum[blockIdx.x] = s[0];
}

__global__ __launch_bounds__(256) void k_scan_small(const int* __restrict__ bsum, int* __restrict__ boff, int nb) {
    __shared__ int s[256];
    int t = threadIdx.x;
    int v = (t < nb) ? bsum[t] : 0;
    s[t] = v;
    __syncthreads();
    for (int off = 1; off < 256; off <<= 1) {
        int x = (t >= off) ? s[t - off] : 0;
        __syncthreads();
        s[t] += x;
        __syncthreads();
    }
    if (t < nb) boff[t] = s[t] - v;  // exclusive
}

__global__ __launch_bounds__(256) void k_scan_final(const int* __restrict__ deg, const int* __restrict__ boff,
                                                    int* __restrict__ row_off, int* __restrict__ cursor, int n) {
    __shared__ int s[256];
    int t = threadIdx.x;
    int i = blockIdx.x * 256 + t;
    int v = (i < n) ? deg[i] : 0;
    s[t] = v;
    __syncthreads();
    for (int off = 1; off < 256; off <<= 1) {
        int x = (t >= off) ? s[t - off] : 0;
        __syncthreads();
        s[t] += x;
        __syncthreads();
    }
    int incl = s[t] + boff[blockIdx.x];
    if (i < n) {
        int ex = incl - v;
        row_off[i] = ex;
        cursor[i]  = ex;
        if (i == n - 1) row_off[n] = incl;
    }
}

__global__ __launch_bounds__(256) void k_fill(const int* __restrict__ src, const int* __restrict__ dst,
                                              const float* __restrict__ dinv, int* __restrict__ cursor,
                                              int2* __restrict__ cpair, int E) {
    int e = blockIdx.x * 256 + threadIdx.x;
    if (e < E) {
        int s = src[e], d = dst[e];
        int pos = atomicAdd(&cursor[d], 1);
        cpair[pos] = make_int2(s, __float_as_int(dinv[s] * dinv[d]));
    }
}

// ---------------- fp32 -> bf16 cast ----------------
__global__ __launch_bounds__(256) void k_cast(const float* __restrict__ X, unsigned short* __restrict__ Y, int n8) {
    int i = blockIdx.x * 256 + threadIdx.x;
    if (i < n8) {
        float4 a = ld4(X + (size_t)i * 8);
        float4 b = ld4(X + (size_t)i * 8 + 4);
        uint4 v = make_uint4(f2bf2(a.x, a.y), f2bf2(a.z, a.w), f2bf2(b.x, b.y), f2bf2(b.z, b.w));
        *reinterpret_cast<uint4*>(Y + (size_t)i * 8) = v;
    }
}

// ---------------- tiled GEMM, NC=128: O[nrows x 128](bf16) = X[nrows x 128](bf16) @ W[128 x 128](f32)
// 256 threads, tile 64x128, thread tile 4x8, fp32 compute, sX padded to 68.
__global__ __launch_bounds__(256) void k_gemm128(const unsigned short* __restrict__ X, const float* __restrict__ W,
                                                 unsigned short* __restrict__ O, int nrows) {
    __shared__ float sW[64 * 128];
    __shared__ float sX[64 * 68];

    const int tid  = threadIdx.x;
    const int tc   = tid & 15;
    const int tr   = tid >> 4;
    const int row0 = blockIdx.x * 64;

    float acc[4][8];
#pragma unroll
    for (int r = 0; r < 4; ++r)
#pragma unroll
        for (int c = 0; c < 8; ++c) acc[r][c] = 0.0f;

    for (int kc = 0; kc < 2; ++kc) {
#pragma unroll
        for (int i = 0; i < 8; ++i) {  // sW: 2048 float4s
            int idx = tid + i * 256;
            int kk = idx >> 5, c4 = idx & 31;
            reinterpret_cast<float4*>(sW)[idx] = ld4(W + (size_t)(kc * 64 + kk) * 128 + c4 * 4);
        }
#pragma unroll
        for (int i = 0; i < 2; ++i) {  // sX: 512 loads of 8 bf16 (16 B)
            int idx = tid + i * 256;
            int r = idx >> 3, c8 = idx & 7;
            int grow = row0 + r;
            uint4 v = make_uint4(0, 0, 0, 0);
            if (grow < nrows) v = *reinterpret_cast<const uint4*>(X + (size_t)grow * 128 + kc * 64 + c8 * 8);
            float f[8];
            unpack8(v, f);
            float* d = &sX[r * 68 + c8 * 8];
            st4(d, make_float4(f[0], f[1], f[2], f[3]));
            st4(d + 4, make_float4(f[4], f[5], f[6], f[7]));
        }
        __syncthreads();

#pragma unroll
        for (int k4 = 0; k4 < 16; ++k4) {
            float4 xa[4];
#pragma unroll
            for (int r = 0; r < 4; ++r)
                xa[r] = *reinterpret_cast<const float4*>(&sX[(tr * 4 + r) * 68 + k4 * 4]);
            float4 wlo[4], whi[4];
#pragma unroll
            for (int j = 0; j < 4; ++j) {
                wlo[j] = *reinterpret_cast<const float4*>(&sW[(k4 * 4 + j) * 128 + tc * 4]);
                whi[j] = *reinterpret_cast<const float4*>(&sW[(k4 * 4 + j) * 128 + 64 + tc * 4]);
            }
#pragma unroll
            for (int r = 0; r < 4; ++r) {
                float xs[4] = {xa[r].x, xa[r].y, xa[r].z, xa[r].w};
#pragma unroll
                for (int j = 0; j < 4; ++j) {
                    acc[r][0] += xs[j] * wlo[j].x;
                    acc[r][1] += xs[j] * wlo[j].y;
                    acc[r][2] += xs[j] * wlo[j].z;
                    acc[r][3] += xs[j] * wlo[j].w;
                    acc[r][4] += xs[j] * whi[j].x;
                    acc[r][5] += xs[j] * whi[j].y;
                    acc[r][6] += xs[j] * whi[j].z;
                    acc[r][7] += xs[j] * whi[j].w;
                }
            }
        }
        __syncthreads();
    }

#pragma unroll
    for (int r = 0; r < 4; ++r) {
        int grow = row0 + tr * 4 + r;
        if (grow < nrows) {
            uint2 lo = make_uint2(f2bf2(acc[r][0], acc[r][1]), f2bf2(acc[r][2], acc[r][3]));
            uint2 hi = make_uint2(f2bf2(acc[r][4], acc[r][5]), f2bf2(acc[r][6], acc[r][7]));
            *reinterpret_cast<uint2*>(O + (size_t)grow * 128 + tc * 4) = lo;
            *reinterpret_cast<uint2*>(O + (size_t)grow * 128 + 64 + tc * 4) = hi;
        }
    }
}

// ---------------- tiled GEMM, NC=64: O bf16 = X[nrows x 128](bf16) @ W[128 x 64](f32) ----------------
__global__ __launch_bounds__(256) void k_gemm64(const unsigned short* __restrict__ X, const float* __restrict__ W,
                                                unsigned short* __restrict__ O, int nrows) {
    __shared__ float sW[64 * 64];
    __shared__ float sX[64 * 68];

    const int tid  = threadIdx.x;
    const int tc   = tid & 15;
    const int tr   = tid >> 4;
    const int row0 = blockIdx.x * 64;

    float acc[4][4];
#pragma unroll
    for (int r = 0; r < 4; ++r)
#pragma unroll
        for (int c = 0; c < 4; ++c) acc[r][c] = 0.0f;

    for (int kc = 0; kc < 2; ++kc) {
#pragma unroll
        for (int i = 0; i < 4; ++i) {  // sW: 1024 float4s
            int idx = tid + i * 256;
            int kk = idx >> 4, c4 = idx & 15;
            reinterpret_cast<float4*>(sW)[idx] = ld4(W + (size_t)(kc * 64 + kk) * 64 + c4 * 4);
        }
#pragma unroll
        for (int i = 0; i < 2; ++i) {
            int idx = tid + i * 256;
            int r = idx >> 3, c8 = idx & 7;
            int grow = row0 + r;
            uint4 v = make_uint4(0, 0, 0, 0);
            if (grow < nrows) v = *reinterpret_cast<const uint4*>(X + (size_t)grow * 128 + kc * 64 + c8 * 8);
            float f[8];
            unpack8(v, f);
            float* d = &sX[r * 68 + c8 * 8];
            st4(d, make_float4(f[0], f[1], f[2], f[3]));
            st4(d + 4, make_float4(f[4], f[5], f[6], f[7]));
        }
        __syncthreads();

#pragma unroll
        for (int k4 = 0; k4 < 16; ++k4) {
            float4 xa[4];
#pragma unroll
            for (int r = 0; r < 4; ++r)
                xa[r] = *reinterpret_cast<const float4*>(&sX[(tr * 4 + r) * 68 + k4 * 4]);
            float4 w[4];
#pragma unroll
            for (int j = 0; j < 4; ++j)
                w[j] = *reinterpret_cast<const float4*>(&sW[(k4 * 4 + j) * 64 + tc * 4]);
#pragma unroll
            for (int r = 0; r < 4; ++r) {
                float xs[4] = {xa[r].x, xa[r].y, xa[r].z, xa[r].w};
#pragma unroll
                for (int j = 0; j < 4; ++j) {
                    acc[r][0] += xs[j] * w[j].x;
                    acc[r][1] += xs[j] * w[j].y;
                    acc[r][2] += xs[j] * w[j].z;
                    acc[r][3] += xs[j] * w[j].w;
                }
            }
        }
        __syncthreads();
    }

#pragma unroll
    for (int r = 0; r < 4; ++r) {
        int grow = row0 + tr * 4 + r;
        if (grow < nrows) {
            uint2 o = make_uint2(f2bf2(acc[r][0], acc[r][1]), f2bf2(acc[r][2], acc[r][3]));
            *reinterpret_cast<uint2*>(O + (size_t)grow * 64 + tc * 4) = o;
        }
    }
}

// ---------------- aggregation (128 feats, bf16 H) + bias + relu ----------------
// 16 lanes per node, 8 feats (16 B) per lane.
__global__ __launch_bounds__(256) void k_agg_relu(const unsigned short* __restrict__ H, const int* __restrict__ roff,
                                                  const int2* __restrict__ cpair, const float* __restrict__ dinv,
                                                  const float* __restrict__ bias, unsigned short* __restrict__ O, int n) {
    int t    = blockIdx.x * 256 + threadIdx.x;
    int node = t >> 4;
    int f8   = (t & 15) * 8;
    if (node >= n) return;

    float di = dinv[node];
    float sc = di * di;
    float a[8];
    {
        uint4 hv = *reinterpret_cast<const uint4*>(H + (size_t)node * 128 + f8);
        float h[8];
        unpack8(hv, h);
#pragma unroll
        for (int i = 0; i < 8; ++i) a[i] = h[i] * sc;
    }

    int e  = roff[node];
    int e1 = roff[node + 1];
    for (; e + 1 < e1; e += 2) {
        int2 p0 = cpair[e], p1 = cpair[e + 1];
        float n0 = __int_as_float(p0.y), n1 = __int_as_float(p1.y);
        uint4 v0 = *reinterpret_cast<const uint4*>(H + (size_t)p0.x * 128 + f8);
        uint4 v1 = *reinterpret_cast<const uint4*>(H + (size_t)p1.x * 128 + f8);
        float g0[8], g1[8];
        unpack8(v0, g0);
        unpack8(v1, g1);
#pragma unroll
        for (int i = 0; i < 8; ++i) a[i] += g0[i] * n0 + g1[i] * n1;
    }
    if (e < e1) {
        int2 p0 = cpair[e];
        float n0 = __int_as_float(p0.y);
        uint4 v0 = *reinterpret_cast<const uint4*>(H + (size_t)p0.x * 128 + f8);
        float g0[8];
        unpack8(v0, g0);
#pragma unroll
        for (int i = 0; i < 8; ++i) a[i] += g0[i] * n0;
    }

    float4 b0 = ld4(bias + f8);
    float4 b1 = ld4(bias + f8 + 4);
    float bb[8] = {b0.x, b0.y, b0.z, b0.w, b1.x, b1.y, b1.z, b1.w};
#pragma unroll
    for (int i = 0; i < 8; ++i) a[i] = fmaxf(a[i] + bb[i], 0.0f);

    uint4 ov = make_uint4(f2bf2(a[0], a[1]), f2bf2(a[2], a[3]), f2bf2(a[4], a[5]), f2bf2(a[6], a[7]));
    *reinterpret_cast<uint4*>(O + (size_t)node * 128 + f8) = ov;
}

// ---------------- aggregation (64 feats, bf16 H) + bias + log_softmax ----------------
// one 64-lane wave per node, fp32 output.
__global__ __launch_bounds__(256) void k_agg_softmax(const unsigned short* __restrict__ H, const int* __restrict__ roff,
                                                     const int2* __restrict__ cpair, const float* __restrict__ dinv,
                                                     const float* __restrict__ bias, float* __restrict__ O, int n) {
    int t    = blockIdx.x * 256 + threadIdx.x;
    int node = t >> 6;
    int f    = t & 63;
    if (node >= n) return;

    float di  = dinv[node];
    float acc = bf2f(H[(size_t)node * 64 + f]) * di * di;

    int e  = roff[node];
    int e1 = roff[node + 1];
    for (; e + 1 < e1; e += 2) {
        int2 p0 = cpair[e], p1 = cpair[e + 1];
        acc += bf2f(H[(size_t)p0.x * 64 + f]) * __int_as_float(p0.y)
             + bf2f(H[(size_t)p1.x * 64 + f]) * __int_as_float(p1.y);
    }
    if (e < e1) {
        int2 p0 = cpair[e];
        acc += bf2f(H[(size_t)p0.x * 64 + f]) * __int_as_float(p0.y);
    }

    float v = acc + bias[f];

    float m = v;
#pragma unroll
    for (int off = 32; off > 0; off >>= 1) m = fmaxf(m, __shfl_xor(m, off));
    float ex = expf(v - m);
    float ssum = ex;
#pragma unroll
    for (int off = 32; off > 0; off >>= 1) ssum += __shfl_xor(ssum, off);

    O[(size_t)node * 64 + f] = (v - m) - logf(ssum);
}

// ---------------- launch ----------------
extern "C" void kernel_launch(void* const* d_in, const int* in_sizes, int n_in,
                              void* d_out, int out_size, void* d_ws, size_t ws_size,
                              hipStream_t stream) {
    const float* x  = (const float*)d_in[0];
    const int*   ei = (const int*)d_in[1];
    const float* W1 = (const float*)d_in[2];
    const float* b1 = (const float*)d_in[3];
    const float* W2 = (const float*)d_in[4];
    const float* b2 = (const float*)d_in[5];
    const float* W3 = (const float*)d_in[6];
    const float* b3 = (const float*)d_in[7];
    float* out = (float*)d_out;

    const int N = in_sizes[0] / 128;
    const int E = in_sizes[1] / 2;
    const int* src = ei;
    const int* dst = ei + E;

    char* ws = (char*)d_ws;
    size_t off = 0;
    auto alloc = [&](size_t bytes) -> char* {
        char* p = ws + off;
        off = (off + bytes + 255) & ~(size_t)255;
        return p;
    };
    int nb = (N + 255) / 256;
    int*   deg     = (int*)alloc((size_t)N * 4);
    int*   cursor  = (int*)alloc((size_t)N * 4);
    int*   row_off = (int*)alloc(((size_t)N + 1) * 4);
    float* dinv    = (float*)alloc((size_t)N * 4);
    int*   bsum    = (int*)alloc((size_t)nb * 4);
    int*   boff    = (int*)alloc((size_t)nb * 4);
    int2*  cpair   = (int2*)alloc((size_t)E * 8);
    unsigned short* xbf  = (unsigned short*)alloc((size_t)N * 128 * 2);  // also reused as H3 (N x 64)
    unsigned short* bufA = (unsigned short*)alloc((size_t)N * 128 * 2);
    unsigned short* bufB = (unsigned short*)alloc((size_t)N * 128 * 2);
    (void)ws_size; (void)n_in; (void)out_size;

    hipMemsetAsync(deg, 0, (size_t)N * 4, stream);
    k_count<<<(E + 255) / 256, 256, 0, stream>>>(dst, deg, E);
    k_dinv<<<(N + 255) / 256, 256, 0, stream>>>(deg, dinv, N);
    k_reduce256<<<nb, 256, 0, stream>>>(deg, bsum, N);
    k_scan_small<<<1, 256, 0, stream>>>(bsum, boff, nb);
    k_scan_final<<<nb, 256, 0, stream>>>(deg, boff, row_off, cursor, N);
    k_fill<<<(E + 255) / 256, 256, 0, stream>>>(src, dst, dinv, cursor, cpair, E);

    // cast x -> bf16
    k_cast<<<((size_t)N * 16 + 255) / 256, 256, 0, stream>>>(x, xbf, N * 16);

    int gemm_blocks = (N + 63) / 64;
    // layer 1
    k_gemm128<<<gemm_blocks, 256, 0, stream>>>(xbf, W1, bufA, N);
    k_agg_relu<<<((size_t)N * 16 + 255) / 256, 256, 0, stream>>>(bufA, row_off, cpair, dinv, b1, bufB, N);
    // layer 2
    k_gemm128<<<gemm_blocks, 256, 0, stream>>>(bufB, W2, bufA, N);
    k_agg_relu<<<((size_t)N * 16 + 255) / 256, 256, 0, stream>>>(bufA, row_off, cpair, dinv, b2, bufB, N);
    // layer 3 + log_softmax (H3 reuses xbf: N x 64 bf16)
    k_gemm64<<<gemm_blocks, 256, 0, stream>>>(bufB, W3, xbf, N);
    k_agg_softmax<<<(N + 3) / 4, 256, 0, stream>>>(xbf, row_off, cpair, dinv, b3, out, N);
}

// Round 4
// 291.752 us; speedup vs baseline: 1.7397x; 1.2972x over previous
//
#include <hip/hip_runtime.h>
#include <math.h>

// ---------------- helpers ----------------
typedef short short8 __attribute__((ext_vector_type(8)));
typedef float floatx4 __attribute__((ext_vector_type(4)));

__device__ __forceinline__ float4 ld4(const float* p) { return *reinterpret_cast<const float4*>(p); }
__device__ __forceinline__ void st4(float* p, float4 v) { *reinterpret_cast<float4*>(p) = v; }

__device__ __forceinline__ float bf2f(unsigned int u) { return __uint_as_float(u << 16); }
__device__ __forceinline__ unsigned int f2bf1(float f) {
    unsigned int x = __float_as_uint(f);
    return (x + 0x7fffu + ((x >> 16) & 1u)) >> 16;  // RNE
}
__device__ __forceinline__ unsigned int f2bf2(float lo, float hi) {
    return f2bf1(lo) | (f2bf1(hi) << 16);
}
__device__ __forceinline__ void unpack8(uint4 v, float* f) {
    f[0] = bf2f(v.x & 0xffffu); f[1] = bf2f(v.x >> 16);
    f[2] = bf2f(v.y & 0xffffu); f[3] = bf2f(v.y >> 16);
    f[4] = bf2f(v.z & 0xffffu); f[5] = bf2f(v.z >> 16);
    f[6] = bf2f(v.w & 0xffffu); f[7] = bf2f(v.w >> 16);
}

// ---------------- CSR build ----------------
__global__ __launch_bounds__(256) void k_count(const int* __restrict__ dst, int* __restrict__ deg, int E) {
    int e = blockIdx.x * 256 + threadIdx.x;
    if (e < E) atomicAdd(&deg[dst[e]], 1);
}

__global__ __launch_bounds__(256) void k_dinv(const int* __restrict__ deg, float* __restrict__ dinv, int n) {
    int i = blockIdx.x * 256 + threadIdx.x;
    if (i < n) dinv[i] = 1.0f / sqrtf((float)deg[i] + 1.0f);
}

__global__ __launch_bounds__(256) void k_reduce256(const int* __restrict__ deg, int* __restrict__ bsum, int n) {
    __shared__ int s[256];
    int t = threadIdx.x;
    int i = blockIdx.x * 256 + t;
    s[t] = (i < n) ? deg[i] : 0;
    __syncthreads();
    for (int off = 128; off > 0; off >>= 1) {
        if (t < off) s[t] += s[t + off];
        __syncthreads();
    }
    if (t == 0) bsum[blockIdx.x] = s[0];
}

__global__ __launch_bounds__(256) void k_scan_small(const int* __restrict__ bsum, int* __restrict__ boff, int nb) {
    __shared__ int s[256];
    int t = threadIdx.x;
    int v = (t < nb) ? bsum[t] : 0;
    s[t] = v;
    __syncthreads();
    for (int off = 1; off < 256; off <<= 1) {
        int x = (t >= off) ? s[t - off] : 0;
        __syncthreads();
        s[t] += x;
        __syncthreads();
    }
    if (t < nb) boff[t] = s[t] - v;  // exclusive
}

__global__ __launch_bounds__(256) void k_scan_final(const int* __restrict__ deg, const int* __restrict__ boff,
                                                    int* __restrict__ row_off, int* __restrict__ cursor, int n) {
    __shared__ int s[256];
    int t = threadIdx.x;
    int i = blockIdx.x * 256 + t;
    int v = (i < n) ? deg[i] : 0;
    s[t] = v;
    __syncthreads();
    for (int off = 1; off < 256; off <<= 1) {
        int x = (t >= off) ? s[t - off] : 0;
        __syncthreads();
        s[t] += x;
        __syncthreads();
    }
    int incl = s[t] + boff[blockIdx.x];
    if (i < n) {
        int ex = incl - v;
        row_off[i] = ex;
        cursor[i]  = ex;
        if (i == n - 1) row_off[n] = incl;
    }
}

__global__ __launch_bounds__(256) void k_fill(const int* __restrict__ src, const int* __restrict__ dst,
                                              const float* __restrict__ dinv, int* __restrict__ cursor,
                                              int2* __restrict__ cpair, int E) {
    int e = blockIdx.x * 256 + threadIdx.x;
    if (e < E) {
        int s = src[e], d = dst[e];
        int pos = atomicAdd(&cursor[d], 1);
        cpair[pos] = make_int2(s, __float_as_int(dinv[s] * dinv[d]));
    }
}

// ---------------- W [128 x NC] f32  ->  Wt [NC x 128] bf16 ----------------
__global__ __launch_bounds__(256) void k_prepW(const float* __restrict__ W, unsigned short* __restrict__ Wt, int NC) {
    int t = blockIdx.x * 256 + threadIdx.x;
    if (t < NC * 128) {
        int k = t & 127, n = t >> 7;
        Wt[n * 128 + k] = (unsigned short)f2bf1(W[(size_t)k * NC + n]);
    }
}

// ---------------- MFMA GEMM: O[nrows x NC](bf16) = X[nrows x 128] @ W[128 x NC] ----------------
// block = 256 threads (4 waves), 64 rows/block (16 rows/wave), full NC width per wave.
// LDS rows padded to 136 shorts (16B-aligned stride, 2-way banks = free).
// mfma_f32_16x16x32_bf16: A=Wt-frag (m=w-col), B=X-frag (n=x-row)
//   => D[row=quad*4+reg = w-col][col=lane&15 = x-row]  => packed 8B stores.
template <int NC, bool XF32>
__global__ __launch_bounds__(256) void k_gemm_mfma(const void* __restrict__ Xv, const unsigned short* __restrict__ Wt,
                                                   unsigned short* __restrict__ O, int nrows) {
    constexpr int LDR = 136;  // shorts per LDS row
    __shared__ unsigned short sX[64 * LDR];
    __shared__ unsigned short sB[NC * LDR];

    const int tid  = threadIdx.x;
    const int row0 = blockIdx.x * 64;

    // ---- stage X[row0..row0+64)[0..128) ----
    if constexpr (XF32) {
        const float* X = (const float*)Xv;
#pragma unroll
        for (int i = 0; i < 4; ++i) {
            int idx = tid + i * 256;           // 1024 chunks of 8 elems
            int r = idx >> 4, c8 = idx & 15;
            int grow = row0 + r;
            uint4 v = make_uint4(0, 0, 0, 0);
            if (grow < nrows) {
                float4 a = ld4(X + (size_t)grow * 128 + c8 * 8);
                float4 b = ld4(X + (size_t)grow * 128 + c8 * 8 + 4);
                v = make_uint4(f2bf2(a.x, a.y), f2bf2(a.z, a.w), f2bf2(b.x, b.y), f2bf2(b.z, b.w));
            }
            *reinterpret_cast<uint4*>(&sX[r * LDR + c8 * 8]) = v;
        }
    } else {
        const unsigned short* X = (const unsigned short*)Xv;
#pragma unroll
        for (int i = 0; i < 4; ++i) {
            int idx = tid + i * 256;
            int r = idx >> 4, c8 = idx & 15;
            int grow = row0 + r;
            uint4 v = make_uint4(0, 0, 0, 0);
            if (grow < nrows) v = *reinterpret_cast<const uint4*>(X + (size_t)grow * 128 + c8 * 8);
            *reinterpret_cast<uint4*>(&sX[r * LDR + c8 * 8]) = v;
        }
    }
    // ---- stage Wt[0..NC)[0..128) ----
#pragma unroll
    for (int i = 0; i < NC / 16; ++i) {
        int idx = tid + i * 256;
        int n = idx >> 4, c8 = idx & 15;
        *reinterpret_cast<uint4*>(&sB[n * LDR + c8 * 8]) =
            *reinterpret_cast<const uint4*>(Wt + (size_t)n * 128 + c8 * 8);
    }
    __syncthreads();

    const int lane = tid & 63;
    const int wave = tid >> 6;
    const int l15  = lane & 15;
    const int quad = lane >> 4;

    floatx4 acc[NC / 16];
#pragma unroll
    for (int j = 0; j < NC / 16; ++j) acc[j] = (floatx4){0.f, 0.f, 0.f, 0.f};

    const unsigned short* xbase = &sX[(wave * 16 + l15) * LDR + quad * 8];
#pragma unroll
    for (int kk = 0; kk < 4; ++kk) {
        short8 xb = *reinterpret_cast<const short8*>(xbase + kk * 32);
#pragma unroll
        for (int j = 0; j < NC / 16; ++j) {
            short8 wa = *reinterpret_cast<const short8*>(&sB[(j * 16 + l15) * LDR + quad * 8 + kk * 32]);
            acc[j] = __builtin_amdgcn_mfma_f32_16x16x32_bf16(wa, xb, acc[j], 0, 0, 0);
        }
    }

    int xrow = row0 + wave * 16 + l15;
    if (xrow < nrows) {
#pragma unroll
        for (int j = 0; j < NC / 16; ++j) {
            uint2 o = make_uint2(f2bf2(acc[j][0], acc[j][1]), f2bf2(acc[j][2], acc[j][3]));
            *reinterpret_cast<uint2*>(O + (size_t)xrow * NC + j * 16 + quad * 4) = o;
        }
    }
}

// ---------------- aggregation (128 feats, bf16 H) + bias + relu ----------------
// 16 lanes per node, 8 feats (16 B) per lane.
__global__ __launch_bounds__(256) void k_agg_relu(const unsigned short* __restrict__ H, const int* __restrict__ roff,
                                                  const int2* __restrict__ cpair, const float* __restrict__ dinv,
                                                  const float* __restrict__ bias, unsigned short* __restrict__ O, int n) {
    int t    = blockIdx.x * 256 + threadIdx.x;
    int node = t >> 4;
    int f8   = (t & 15) * 8;
    if (node >= n) return;

    float di = dinv[node];
    float sc = di * di;
    float a[8];
    {
        uint4 hv = *reinterpret_cast<const uint4*>(H + (size_t)node * 128 + f8);
        float h[8];
        unpack8(hv, h);
#pragma unroll
        for (int i = 0; i < 8; ++i) a[i] = h[i] * sc;
    }

    int e  = roff[node];
    int e1 = roff[node + 1];
    for (; e + 1 < e1; e += 2) {
        int2 p0 = cpair[e], p1 = cpair[e + 1];
        float n0 = __int_as_float(p0.y), n1 = __int_as_float(p1.y);
        uint4 v0 = *reinterpret_cast<const uint4*>(H + (size_t)p0.x * 128 + f8);
        uint4 v1 = *reinterpret_cast<const uint4*>(H + (size_t)p1.x * 128 + f8);
        float g0[8], g1[8];
        unpack8(v0, g0);
        unpack8(v1, g1);
#pragma unroll
        for (int i = 0; i < 8; ++i) a[i] += g0[i] * n0 + g1[i] * n1;
    }
    if (e < e1) {
        int2 p0 = cpair[e];
        float n0 = __int_as_float(p0.y);
        uint4 v0 = *reinterpret_cast<const uint4*>(H + (size_t)p0.x * 128 + f8);
        float g0[8];
        unpack8(v0, g0);
#pragma unroll
        for (int i = 0; i < 8; ++i) a[i] += g0[i] * n0;
    }

    float4 b0 = ld4(bias + f8);
    float4 b1 = ld4(bias + f8 + 4);
    float bb[8] = {b0.x, b0.y, b0.z, b0.w, b1.x, b1.y, b1.z, b1.w};
#pragma unroll
    for (int i = 0; i < 8; ++i) a[i] = fmaxf(a[i] + bb[i], 0.0f);

    uint4 ov = make_uint4(f2bf2(a[0], a[1]), f2bf2(a[2], a[3]), f2bf2(a[4], a[5]), f2bf2(a[6], a[7]));
    *reinterpret_cast<uint4*>(O + (size_t)node * 128 + f8) = ov;
}

// ---------------- aggregation (64 feats, bf16 H) + bias + log_softmax ----------------
// 8 lanes per node, 8 feats (uint4) per lane; softmax via reg-reduce + shfl_xor(1,2,4).
__global__ __launch_bounds__(256) void k_agg_softmax(const unsigned short* __restrict__ H, const int* __restrict__ roff,
                                                     const int2* __restrict__ cpair, const float* __restrict__ dinv,
                                                     const float* __restrict__ bias, float* __restrict__ O, int n) {
    int t    = blockIdx.x * 256 + threadIdx.x;
    int node = t >> 3;
    int f8   = (t & 7) * 8;
    if (node >= n) return;

    float di = dinv[node];
    float sc = di * di;
    float a[8];
    {
        uint4 hv = *reinterpret_cast<const uint4*>(H + (size_t)node * 64 + f8);
        float h[8];
        unpack8(hv, h);
#pragma unroll
        for (int i = 0; i < 8; ++i) a[i] = h[i] * sc;
    }

    int e  = roff[node];
    int e1 = roff[node + 1];
    for (; e + 1 < e1; e += 2) {
        int2 p0 = cpair[e], p1 = cpair[e + 1];
        float n0 = __int_as_float(p0.y), n1 = __int_as_float(p1.y);
        uint4 v0 = *reinterpret_cast<const uint4*>(H + (size_t)p0.x * 64 + f8);
        uint4 v1 = *reinterpret_cast<const uint4*>(H + (size_t)p1.x * 64 + f8);
        float g0[8], g1[8];
        unpack8(v0, g0);
        unpack8(v1, g1);
#pragma unroll
        for (int i = 0; i < 8; ++i) a[i] += g0[i] * n0 + g1[i] * n1;
    }
    if (e < e1) {
        int2 p0 = cpair[e];
        float n0 = __int_as_float(p0.y);
        uint4 v0 = *reinterpret_cast<const uint4*>(H + (size_t)p0.x * 64 + f8);
        float g0[8];
        unpack8(v0, g0);
#pragma unroll
        for (int i = 0; i < 8; ++i) a[i] += g0[i] * n0;
    }

    float4 b0 = ld4(bias + f8);
    float4 b1 = ld4(bias + f8 + 4);
    float bb[8] = {b0.x, b0.y, b0.z, b0.w, b1.x, b1.y, b1.z, b1.w};
    float v[8];
#pragma unroll
    for (int i = 0; i < 8; ++i) v[i] = a[i] + bb[i];

    float m = v[0];
#pragma unroll
    for (int i = 1; i < 8; ++i) m = fmaxf(m, v[i]);
    m = fmaxf(m, __shfl_xor(m, 1));
    m = fmaxf(m, __shfl_xor(m, 2));
    m = fmaxf(m, __shfl_xor(m, 4));

    float ssum = 0.0f;
#pragma unroll
    for (int i = 0; i < 8; ++i) ssum += expf(v[i] - m);
    ssum += __shfl_xor(ssum, 1);
    ssum += __shfl_xor(ssum, 2);
    ssum += __shfl_xor(ssum, 4);
    float ls = logf(ssum);

    float* op = O + (size_t)node * 64 + f8;
    st4(op, make_float4(v[0] - m - ls, v[1] - m - ls, v[2] - m - ls, v[3] - m - ls));
    st4(op + 4, make_float4(v[4] - m - ls, v[5] - m - ls, v[6] - m - ls, v[7] - m - ls));
}

// ---------------- launch ----------------
extern "C" void kernel_launch(void* const* d_in, const int* in_sizes, int n_in,
                              void* d_out, int out_size, void* d_ws, size_t ws_size,
                              hipStream_t stream) {
    const float* x  = (const float*)d_in[0];
    const int*   ei = (const int*)d_in[1];
    const float* W1 = (const float*)d_in[2];
    const float* b1 = (const float*)d_in[3];
    const float* W2 = (const float*)d_in[4];
    const float* b2 = (const float*)d_in[5];
    const float* W3 = (const float*)d_in[6];
    const float* b3 = (const float*)d_in[7];
    float* out = (float*)d_out;

    const int N = in_sizes[0] / 128;
    const int E = in_sizes[1] / 2;
    const int* src = ei;
    const int* dst = ei + E;

    char* ws = (char*)d_ws;
    size_t off = 0;
    auto alloc = [&](size_t bytes) -> char* {
        char* p = ws + off;
        off = (off + bytes + 255) & ~(size_t)255;
        return p;
    };
    int nb = (N + 255) / 256;
    int*   deg     = (int*)alloc((size_t)N * 4);
    int*   cursor  = (int*)alloc((size_t)N * 4);
    int*   row_off = (int*)alloc(((size_t)N + 1) * 4);
    float* dinv    = (float*)alloc((size_t)N * 4);
    int*   bsum    = (int*)alloc((size_t)nb * 4);
    int*   boff    = (int*)alloc((size_t)nb * 4);
    int2*  cpair   = (int2*)alloc((size_t)E * 8);
    unsigned short* Wt1  = (unsigned short*)alloc(128 * 128 * 2);
    unsigned short* Wt2  = (unsigned short*)alloc(128 * 128 * 2);
    unsigned short* Wt3  = (unsigned short*)alloc(64 * 128 * 2);
    unsigned short* bufA = (unsigned short*)alloc((size_t)N * 128 * 2);
    unsigned short* bufB = (unsigned short*)alloc((size_t)N * 128 * 2);
    unsigned short* bufC = (unsigned short*)alloc((size_t)N * 64 * 2);
    (void)ws_size; (void)n_in; (void)out_size;

    hipMemsetAsync(deg, 0, (size_t)N * 4, stream);
    k_count<<<(E + 255) / 256, 256, 0, stream>>>(dst, deg, E);
    k_dinv<<<(N + 255) / 256, 256, 0, stream>>>(deg, dinv, N);
    k_reduce256<<<nb, 256, 0, stream>>>(deg, bsum, N);
    k_scan_small<<<1, 256, 0, stream>>>(bsum, boff, nb);
    k_scan_final<<<nb, 256, 0, stream>>>(deg, boff, row_off, cursor, N);
    k_fill<<<(E + 255) / 256, 256, 0, stream>>>(src, dst, dinv, cursor, cpair, E);

    k_prepW<<<(128 * 128 + 255) / 256, 256, 0, stream>>>(W1, Wt1, 128);
    k_prepW<<<(128 * 128 + 255) / 256, 256, 0, stream>>>(W2, Wt2, 128);
    k_prepW<<<(64 * 128 + 255) / 256, 256, 0, stream>>>(W3, Wt3, 64);

    int gemm_blocks = (N + 63) / 64;
    // layer 1 (f32 x converted during staging)
    k_gemm_mfma<128, true><<<gemm_blocks, 256, 0, stream>>>(x, Wt1, bufA, N);
    k_agg_relu<<<((size_t)N * 16 + 255) / 256, 256, 0, stream>>>(bufA, row_off, cpair, dinv, b1, bufB, N);
    // layer 2
    k_gemm_mfma<128, false><<<gemm_blocks, 256, 0, stream>>>(bufB, Wt2, bufA, N);
    k_agg_relu<<<((size_t)N * 16 + 255) / 256, 256, 0, stream>>>(bufA, row_off, cpair, dinv, b2, bufB, N);
    // layer 3 + log_softmax
    k_gemm_mfma<64, false><<<gemm_blocks, 256, 0, stream>>>(bufB, Wt3, bufC, N);
    k_agg_softmax<<<((size_t)N * 8 + 255) / 256, 256, 0, stream>>>(bufC, row_off, cpair, dinv, b3, out, N);
}

// Round 5
// 257.736 us; speedup vs baseline: 1.9693x; 1.1320x over previous
//
#include <hip/hip_runtime.h>
#include <math.h>

// ---------------- helpers ----------------
typedef short short8 __attribute__((ext_vector_type(8)));
typedef float floatx4 __attribute__((ext_vector_type(4)));

__device__ __forceinline__ float4 ld4(const float* p) { return *reinterpret_cast<const float4*>(p); }
__device__ __forceinline__ void st4(float* p, float4 v) { *reinterpret_cast<float4*>(p) = v; }

__device__ __forceinline__ float bf2f(unsigned int u) { return __uint_as_float(u << 16); }
__device__ __forceinline__ unsigned int f2bf1(float f) {
    unsigned int x = __float_as_uint(f);
    return (x + 0x7fffu + ((x >> 16) & 1u)) >> 16;  // RNE
}
__device__ __forceinline__ unsigned int f2bf2(float lo, float hi) {
    return f2bf1(lo) | (f2bf1(hi) << 16);
}
__device__ __forceinline__ void unpack8(uint4 v, float* f) {
    f[0] = bf2f(v.x & 0xffffu); f[1] = bf2f(v.x >> 16);
    f[2] = bf2f(v.y & 0xffffu); f[3] = bf2f(v.y >> 16);
    f[4] = bf2f(v.z & 0xffffu); f[5] = bf2f(v.z >> 16);
    f[6] = bf2f(v.w & 0xffffu); f[7] = bf2f(v.w >> 16);
}

// ---------------- CSR build ----------------
// count + per-edge rank (atomicAdd return value = within-row slot)
__global__ __launch_bounds__(256) void k_count(const int* __restrict__ dst, int* __restrict__ deg,
                                               int* __restrict__ rank, int E) {
    int e = blockIdx.x * 256 + threadIdx.x;
    if (e < E) rank[e] = atomicAdd(&deg[dst[e]], 1);
}

__global__ __launch_bounds__(256) void k_reduce256(const int* __restrict__ deg, int* __restrict__ bsum, int n) {
    __shared__ int s[256];
    int t = threadIdx.x;
    int i = blockIdx.x * 256 + t;
    s[t] = (i < n) ? deg[i] : 0;
    __syncthreads();
    for (int off = 128; off > 0; off >>= 1) {
        if (t < off) s[t] += s[t + off];
        __syncthreads();
    }
    if (t == 0) bsum[blockIdx.x] = s[0];
}

__global__ __launch_bounds__(256) void k_scan_small(const int* __restrict__ bsum, int* __restrict__ boff, int nb) {
    __shared__ int s[256];
    int t = threadIdx.x;
    int v = (t < nb) ? bsum[t] : 0;
    s[t] = v;
    __syncthreads();
    for (int off = 1; off < 256; off <<= 1) {
        int x = (t >= off) ? s[t - off] : 0;
        __syncthreads();
        s[t] += x;
        __syncthreads();
    }
    if (t < nb) boff[t] = s[t] - v;  // exclusive
}

// final scan; also emits dinv = 1/sqrt(deg+1)
__global__ __launch_bounds__(256) void k_scan_final(const int* __restrict__ deg, const int* __restrict__ boff,
                                                    int* __restrict__ row_off, float* __restrict__ dinv, int n) {
    __shared__ int s[256];
    int t = threadIdx.x;
    int i = blockIdx.x * 256 + t;
    int v = (i < n) ? deg[i] : 0;
    s[t] = v;
    __syncthreads();
    for (int off = 1; off < 256; off <<= 1) {
        int x = (t >= off) ? s[t - off] : 0;
        __syncthreads();
        s[t] += x;
        __syncthreads();
    }
    int incl = s[t] + boff[blockIdx.x];
    if (i < n) {
        row_off[i] = incl - v;
        dinv[i]    = 1.0f / sqrtf((float)v + 1.0f);
        if (i == n - 1) row_off[n] = incl;
    }
}

// atomic-free fill: pos = row_off[dst] + rank
__global__ __launch_bounds__(256) void k_fill(const int* __restrict__ src, const int* __restrict__ dst,
                                              const int* __restrict__ rank, const int* __restrict__ roff,
                                              const float* __restrict__ dinv, int2* __restrict__ cpair, int E) {
    int e = blockIdx.x * 256 + threadIdx.x;
    if (e < E) {
        int s = src[e], d = dst[e];
        int pos = roff[d] + rank[e];
        cpair[pos] = make_int2(s, __float_as_int(dinv[s] * dinv[d]));
    }
}

// ---------------- all three W -> Wt (bf16, transposed) in one launch ----------------
// W1 [128x128], W2 [128x128], W3 [128x64]
__global__ __launch_bounds__(256) void k_prepW(const float* __restrict__ W1, const float* __restrict__ W2,
                                               const float* __restrict__ W3, unsigned short* __restrict__ Wt1,
                                               unsigned short* __restrict__ Wt2, unsigned short* __restrict__ Wt3) {
    int t = blockIdx.x * 256 + threadIdx.x;
    if (t < 16384) {
        int k = t & 127, n = t >> 7;
        Wt1[n * 128 + k] = (unsigned short)f2bf1(W1[(size_t)k * 128 + n]);
    } else if (t < 32768) {
        int u = t - 16384;
        int k = u & 127, n = u >> 7;
        Wt2[n * 128 + k] = (unsigned short)f2bf1(W2[(size_t)k * 128 + n]);
    } else if (t < 40960) {
        int u = t - 32768;
        int k = u & 127, n = u >> 7;
        Wt3[n * 128 + k] = (unsigned short)f2bf1(W3[(size_t)k * 64 + n]);
    }
}

// ---------------- MFMA GEMM: O[nrows x NC](bf16) = X[nrows x 128] @ W[128 x NC] ----------------
// block = 256 threads (4 waves), 64 rows/block (16 rows/wave), full NC width per wave.
// LDS rows padded to 136 shorts. A=Wt-frag (m=w-col), B=X-frag (n=x-row)
//   => D[row=quad*4+reg = w-col][col=lane&15 = x-row]  => packed 8B stores.
template <int NC, bool XF32>
__global__ __launch_bounds__(256) void k_gemm_mfma(const void* __restrict__ Xv, const unsigned short* __restrict__ Wt,
                                                   unsigned short* __restrict__ O, int nrows) {
    constexpr int LDR = 136;  // shorts per LDS row
    __shared__ unsigned short sX[64 * LDR];
    __shared__ unsigned short sB[NC * LDR];

    const int tid  = threadIdx.x;
    const int row0 = blockIdx.x * 64;

    if constexpr (XF32) {
        const float* X = (const float*)Xv;
#pragma unroll
        for (int i = 0; i < 4; ++i) {
            int idx = tid + i * 256;           // 1024 chunks of 8 elems
            int r = idx >> 4, c8 = idx & 15;
            int grow = row0 + r;
            uint4 v = make_uint4(0, 0, 0, 0);
            if (grow < nrows) {
                float4 a = ld4(X + (size_t)grow * 128 + c8 * 8);
                float4 b = ld4(X + (size_t)grow * 128 + c8 * 8 + 4);
                v = make_uint4(f2bf2(a.x, a.y), f2bf2(a.z, a.w), f2bf2(b.x, b.y), f2bf2(b.z, b.w));
            }
            *reinterpret_cast<uint4*>(&sX[r * LDR + c8 * 8]) = v;
        }
    } else {
        const unsigned short* X = (const unsigned short*)Xv;
#pragma unroll
        for (int i = 0; i < 4; ++i) {
            int idx = tid + i * 256;
            int r = idx >> 4, c8 = idx & 15;
            int grow = row0 + r;
            uint4 v = make_uint4(0, 0, 0, 0);
            if (grow < nrows) v = *reinterpret_cast<const uint4*>(X + (size_t)grow * 128 + c8 * 8);
            *reinterpret_cast<uint4*>(&sX[r * LDR + c8 * 8]) = v;
        }
    }
#pragma unroll
    for (int i = 0; i < NC / 16; ++i) {
        int idx = tid + i * 256;
        int n = idx >> 4, c8 = idx & 15;
        *reinterpret_cast<uint4*>(&sB[n * LDR + c8 * 8]) =
            *reinterpret_cast<const uint4*>(Wt + (size_t)n * 128 + c8 * 8);
    }
    __syncthreads();

    const int lane = tid & 63;
    const int wave = tid >> 6;
    const int l15  = lane & 15;
    const int quad = lane >> 4;

    floatx4 acc[NC / 16];
#pragma unroll
    for (int j = 0; j < NC / 16; ++j) acc[j] = (floatx4){0.f, 0.f, 0.f, 0.f};

    const unsigned short* xbase = &sX[(wave * 16 + l15) * LDR + quad * 8];
#pragma unroll
    for (int kk = 0; kk < 4; ++kk) {
        short8 xb = *reinterpret_cast<const short8*>(xbase + kk * 32);
#pragma unroll
        for (int j = 0; j < NC / 16; ++j) {
            short8 wa = *reinterpret_cast<const short8*>(&sB[(j * 16 + l15) * LDR + quad * 8 + kk * 32]);
            acc[j] = __builtin_amdgcn_mfma_f32_16x16x32_bf16(wa, xb, acc[j], 0, 0, 0);
        }
    }

    int xrow = row0 + wave * 16 + l15;
    if (xrow < nrows) {
#pragma unroll
        for (int j = 0; j < NC / 16; ++j) {
            uint2 o = make_uint2(f2bf2(acc[j][0], acc[j][1]), f2bf2(acc[j][2], acc[j][3]));
            *reinterpret_cast<uint2*>(O + (size_t)xrow * NC + j * 16 + quad * 4) = o;
        }
    }
}

// ---------------- aggregation (128 feats, bf16 H) + bias + relu ----------------
// 16 lanes per node, 8 feats (16 B) per lane; edge loop unrolled x4 for MLP.
__global__ __launch_bounds__(256) void k_agg_relu(const unsigned short* __restrict__ H, const int* __restrict__ roff,
                                                  const int2* __restrict__ cpair, const float* __restrict__ dinv,
                                                  const float* __restrict__ bias, unsigned short* __restrict__ O, int n) {
    int t    = blockIdx.x * 256 + threadIdx.x;
    int node = t >> 4;
    int f8   = (t & 15) * 8;
    if (node >= n) return;

    float di = dinv[node];
    float sc = di * di;
    float a[8];
    {
        uint4 hv = *reinterpret_cast<const uint4*>(H + (size_t)node * 128 + f8);
        float h[8];
        unpack8(hv, h);
#pragma unroll
        for (int i = 0; i < 8; ++i) a[i] = h[i] * sc;
    }

    int e  = roff[node];
    int e1 = roff[node + 1];
    for (; e + 3 < e1; e += 4) {
        int2 p[4];
        uint4 v[4];
#pragma unroll
        for (int u = 0; u < 4; ++u) p[u] = cpair[e + u];
#pragma unroll
        for (int u = 0; u < 4; ++u) v[u] = *reinterpret_cast<const uint4*>(H + (size_t)p[u].x * 128 + f8);
#pragma unroll
        for (int u = 0; u < 4; ++u) {
            float nu = __int_as_float(p[u].y);
            float g[8];
            unpack8(v[u], g);
#pragma unroll
            for (int i = 0; i < 8; ++i) a[i] += g[i] * nu;
        }
    }
    for (; e < e1; ++e) {
        int2 p0 = cpair[e];
        float n0 = __int_as_float(p0.y);
        uint4 v0 = *reinterpret_cast<const uint4*>(H + (size_t)p0.x * 128 + f8);
        float g0[8];
        unpack8(v0, g0);
#pragma unroll
        for (int i = 0; i < 8; ++i) a[i] += g0[i] * n0;
    }

    float4 b0 = ld4(bias + f8);
    float4 b1 = ld4(bias + f8 + 4);
    float bb[8] = {b0.x, b0.y, b0.z, b0.w, b1.x, b1.y, b1.z, b1.w};
#pragma unroll
    for (int i = 0; i < 8; ++i) a[i] = fmaxf(a[i] + bb[i], 0.0f);

    uint4 ov = make_uint4(f2bf2(a[0], a[1]), f2bf2(a[2], a[3]), f2bf2(a[4], a[5]), f2bf2(a[6], a[7]));
    *reinterpret_cast<uint4*>(O + (size_t)node * 128 + f8) = ov;
}

// ---------------- aggregation (64 feats, bf16 H) + bias + log_softmax ----------------
// 8 lanes per node, 8 feats (uint4) per lane; edge loop unrolled x4.
__global__ __launch_bounds__(256) void k_agg_softmax(const unsigned short* __restrict__ H, const int* __restrict__ roff,
                                                     const int2* __restrict__ cpair, const float* __restrict__ dinv,
                                                     const float* __restrict__ bias, float* __restrict__ O, int n) {
    int t    = blockIdx.x * 256 + threadIdx.x;
    int node = t >> 3;
    int f8   = (t & 7) * 8;
    if (node >= n) return;

    float di = dinv[node];
    float sc = di * di;
    float a[8];
    {
        uint4 hv = *reinterpret_cast<const uint4*>(H + (size_t)node * 64 + f8);
        float h[8];
        unpack8(hv, h);
#pragma unroll
        for (int i = 0; i < 8; ++i) a[i] = h[i] * sc;
    }

    int e  = roff[node];
    int e1 = roff[node + 1];
    for (; e + 3 < e1; e += 4) {
        int2 p[4];
        uint4 v[4];
#pragma unroll
        for (int u = 0; u < 4; ++u) p[u] = cpair[e + u];
#pragma unroll
        for (int u = 0; u < 4; ++u) v[u] = *reinterpret_cast<const uint4*>(H + (size_t)p[u].x * 64 + f8);
#pragma unroll
        for (int u = 0; u < 4; ++u) {
            float nu = __int_as_float(p[u].y);
            float g[8];
            unpack8(v[u], g);
#pragma unroll
            for (int i = 0; i < 8; ++i) a[i] += g[i] * nu;
        }
    }
    for (; e < e1; ++e) {
        int2 p0 = cpair[e];
        float n0 = __int_as_float(p0.y);
        uint4 v0 = *reinterpret_cast<const uint4*>(H + (size_t)p0.x * 64 + f8);
        float g0[8];
        unpack8(v0, g0);
#pragma unroll
        for (int i = 0; i < 8; ++i) a[i] += g0[i] * n0;
    }

    float4 b0 = ld4(bias + f8);
    float4 b1 = ld4(bias + f8 + 4);
    float bb[8] = {b0.x, b0.y, b0.z, b0.w, b1.x, b1.y, b1.z, b1.w};
    float v[8];
#pragma unroll
    for (int i = 0; i < 8; ++i) v[i] = a[i] + bb[i];

    float m = v[0];
#pragma unroll
    for (int i = 1; i < 8; ++i) m = fmaxf(m, v[i]);
    m = fmaxf(m, __shfl_xor(m, 1));
    m = fmaxf(m, __shfl_xor(m, 2));
    m = fmaxf(m, __shfl_xor(m, 4));

    float ssum = 0.0f;
#pragma unroll
    for (int i = 0; i < 8; ++i) ssum += expf(v[i] - m);
    ssum += __shfl_xor(ssum, 1);
    ssum += __shfl_xor(ssum, 2);
    ssum += __shfl_xor(ssum, 4);
    float ls = logf(ssum);

    float* op = O + (size_t)node * 64 + f8;
    st4(op, make_float4(v[0] - m - ls, v[1] - m - ls, v[2] - m - ls, v[3] - m - ls));
    st4(op + 4, make_float4(v[4] - m - ls, v[5] - m - ls, v[6] - m - ls, v[7] - m - ls));
}

// ---------------- launch ----------------
extern "C" void kernel_launch(void* const* d_in, const int* in_sizes, int n_in,
                              void* d_out, int out_size, void* d_ws, size_t ws_size,
                              hipStream_t stream) {
    const float* x  = (const float*)d_in[0];
    const int*   ei = (const int*)d_in[1];
    const float* W1 = (const float*)d_in[2];
    const float* b1 = (const float*)d_in[3];
    const float* W2 = (const float*)d_in[4];
    const float* b2 = (const float*)d_in[5];
    const float* W3 = (const float*)d_in[6];
    const float* b3 = (const float*)d_in[7];
    float* out = (float*)d_out;

    const int N = in_sizes[0] / 128;
    const int E = in_sizes[1] / 2;
    const int* src = ei;
    const int* dst = ei + E;

    char* ws = (char*)d_ws;
    size_t off = 0;
    auto alloc = [&](size_t bytes) -> char* {
        char* p = ws + off;
        off = (off + bytes + 255) & ~(size_t)255;
        return p;
    };
    int nb = (N + 255) / 256;
    int*   deg     = (int*)alloc((size_t)N * 4);
    int*   row_off = (int*)alloc(((size_t)N + 1) * 4);
    float* dinv    = (float*)alloc((size_t)N * 4);
    int*   bsum    = (int*)alloc((size_t)nb * 4);
    int*   boff    = (int*)alloc((size_t)nb * 4);
    int*   rank    = (int*)alloc((size_t)E * 4);
    int2*  cpair   = (int2*)alloc((size_t)E * 8);
    unsigned short* Wt1  = (unsigned short*)alloc(128 * 128 * 2);
    unsigned short* Wt2  = (unsigned short*)alloc(128 * 128 * 2);
    unsigned short* Wt3  = (unsigned short*)alloc(64 * 128 * 2);
    unsigned short* bufA = (unsigned short*)alloc((size_t)N * 128 * 2);
    unsigned short* bufB = (unsigned short*)alloc((size_t)N * 128 * 2);
    unsigned short* bufC = (unsigned short*)alloc((size_t)N * 64 * 2);
    (void)ws_size; (void)n_in; (void)out_size;

    hipMemsetAsync(deg, 0, (size_t)N * 4, stream);
    k_count<<<(E + 255) / 256, 256, 0, stream>>>(dst, deg, rank, E);
    k_reduce256<<<nb, 256, 0, stream>>>(deg, bsum, N);
    k_scan_small<<<1, 256, 0, stream>>>(bsum, boff, nb);
    k_scan_final<<<nb, 256, 0, stream>>>(deg, boff, row_off, dinv, N);
    k_fill<<<(E + 255) / 256, 256, 0, stream>>>(src, dst, rank, row_off, dinv, cpair, E);

    k_prepW<<<(40960 + 255) / 256, 256, 0, stream>>>(W1, W2, W3, Wt1, Wt2, Wt3);

    int gemm_blocks = (N + 63) / 64;
    // layer 1 (f32 x converted during staging)
    k_gemm_mfma<128, true><<<gemm_blocks, 256, 0, stream>>>(x, Wt1, bufA, N);
    k_agg_relu<<<((size_t)N * 16 + 255) / 256, 256, 0, stream>>>(bufA, row_off, cpair, dinv, b1, bufB, N);
    // layer 2
    k_gemm_mfma<128, false><<<gemm_blocks, 256, 0, stream>>>(bufB, Wt2, bufA, N);
    k_agg_relu<<<((size_t)N * 16 + 255) / 256, 256, 0, stream>>>(bufA, row_off, cpair, dinv, b2, bufB, N);
    // layer 3 + log_softmax
    k_gemm_mfma<64, false><<<gemm_blocks, 256, 0, stream>>>(bufB, Wt3, bufC, N);
    k_agg_softmax<<<((size_t)N * 8 + 255) / 256, 256, 0, stream>>>(bufC, row_off, cpair, dinv, b3, out, N);
}